// Round 2
// baseline (790.737 us; speedup 1.0000x reference)
//
#include <hip/hip_runtime.h>

typedef __bf16 bf16;
typedef __bf16 bf16x4 __attribute__((ext_vector_type(4)));
typedef __bf16 bf16x8 __attribute__((ext_vector_type(8)));
typedef float f32x4 __attribute__((ext_vector_type(4)));

#define EMBED 1024
#define SEQ   2048
#define NH    16
#define DH    64
#define MROWS 4096   // B*S

__device__ __forceinline__ void gload16(const void* g, void* l) {
    __builtin_amdgcn_global_load_lds((const __attribute__((address_space(1))) void*)g,
                                     (__attribute__((address_space(3))) void*)l,
                                     16, 0, 0);
}

// ---------------- convert X (fp32 -> bf16) ----------------
__global__ __launch_bounds__(256) void cvt_x_kernel(const float* __restrict__ x,
                                                    bf16* __restrict__ xb) {
    int i = (blockIdx.x * 256 + threadIdx.x) * 4;
    float4 v = *(const float4*)(x + i);
    bf16x4 o;
    o[0] = (bf16)v.x; o[1] = (bf16)v.y; o[2] = (bf16)v.z; o[3] = (bf16)v.w;
    *(bf16x4*)(xb + i) = o;
}

// ------------- transpose + convert weights: Wb[n][k] = W[k][n] -------------
__global__ __launch_bounds__(256) void cvt_wt_kernel(
        const float* __restrict__ w0, const float* __restrict__ w1,
        const float* __restrict__ w2, const float* __restrict__ w3,
        bf16* __restrict__ o0, bf16* __restrict__ o1,
        bf16* __restrict__ o2, bf16* __restrict__ o3) {
    const float* w; bf16* o;
    switch (blockIdx.z) {
        case 0: w = w0; o = o0; break;
        case 1: w = w1; o = o1; break;
        case 2: w = w2; o = o2; break;
        default: w = w3; o = o3; break;
    }
    __shared__ float t[32][33];
    int tx = threadIdx.x & 31, ty = threadIdx.x >> 5;      // 32 x 8
    int c0 = blockIdx.x * 32, r0 = blockIdx.y * 32;
    #pragma unroll
    for (int i = 0; i < 32; i += 8)
        t[ty + i][tx] = w[(size_t)(r0 + ty + i) * EMBED + c0 + tx];
    __syncthreads();
    #pragma unroll
    for (int i = 0; i < 32; i += 8)
        o[(size_t)(c0 + ty + i) * EMBED + r0 + tx] = (bf16)t[tx][ty + i];
}

// ---------------- zero the row-sum buffer ----------------
__global__ __launch_bounds__(256) void zero_l_kernel(float* __restrict__ l) {
    int i = (blockIdx.x * 256 + threadIdx.x) * 4;
    f32x4 z = {};
    *(f32x4*)(l + i) = z;
}

// ---------------- 128x128x64 bf16 MFMA GEMM body ----------------
// MODE 0: bf16 row-major [M][1024]; MODE 1: fp32 row-major; MODE 2: Vt[bh][d][s] bf16
template <int MODE>
__device__ __forceinline__ void gemm_body(const bf16* __restrict__ A,
                                          const bf16* __restrict__ Bm,
                                          const float* __restrict__ bias,
                                          void* __restrict__ Cout) {
    __shared__ bf16 As[128 * 64];
    __shared__ bf16 Bs[128 * 64];
    const int tid = threadIdx.x, wave = tid >> 6, lane = tid & 63;
    const int qd = lane >> 4, ln = lane & 15;
    const int m0 = blockIdx.y * 128, n0 = blockIdx.x * 128;
    const int wr = (wave >> 1) * 64, wc = (wave & 1) * 64;
    const int lrow8 = lane >> 3, lcol8 = (lane & 7) * 8;
    f32x4 acc[4][4] = {};

    for (int k0 = 0; k0 < EMBED; k0 += 64) {
        #pragma unroll
        for (int i = 0; i < 4; ++i) {
            int seg = i * 4 + wave;                       // 0..15, wave-uniform
            const bf16* ga = A  + (size_t)(m0 + seg * 8 + lrow8) * EMBED + k0 + lcol8;
            const bf16* gb = Bm + (size_t)(n0 + seg * 8 + lrow8) * EMBED + k0 + lcol8;
            gload16(ga, As + seg * 512);
            gload16(gb, Bs + seg * 512);
        }
        __syncthreads();
        #pragma unroll
        for (int kk = 0; kk < 64; kk += 32) {
            bf16x8 af[4], bfr[4];
            #pragma unroll
            for (int mt = 0; mt < 4; ++mt)
                af[mt] = *(const bf16x8*)(As + (wr + mt * 16 + ln) * 64 + kk + qd * 8);
            #pragma unroll
            for (int nt = 0; nt < 4; ++nt)
                bfr[nt] = *(const bf16x8*)(Bs + (wc + nt * 16 + ln) * 64 + kk + qd * 8);
            #pragma unroll
            for (int mt = 0; mt < 4; ++mt)
                #pragma unroll
                for (int nt = 0; nt < 4; ++nt)
                    acc[mt][nt] = __builtin_amdgcn_mfma_f32_16x16x32_bf16(
                        af[mt], bfr[nt], acc[mt][nt], 0, 0, 0);
        }
        __syncthreads();
    }
    if (MODE == 2) {
        // store to Vt[bh][d][s] with packed bf16x4 (4 consecutive tokens per lane)
        const int b = m0 >> 11;
        const int sbase = (m0 & 2047) + wr;
        #pragma unroll
        for (int mt = 0; mt < 4; ++mt) {
            #pragma unroll
            for (int nt = 0; nt < 4; ++nt) {
                int col = n0 + wc + nt * 16 + ln;
                int h = col >> 6, d = col & 63;
                float bv = bias[col];
                bf16x4 pk;
                #pragma unroll
                for (int r = 0; r < 4; ++r) pk[r] = (bf16)(acc[mt][nt][r] + bv);
                *(bf16x4*)((bf16*)Cout +
                    ((size_t)(b * NH + h) * DH + d) * SEQ + sbase + mt * 16 + qd * 4) = pk;
            }
        }
    } else {
        #pragma unroll
        for (int mt = 0; mt < 4; ++mt) {
            #pragma unroll
            for (int nt = 0; nt < 4; ++nt) {
                int col = n0 + wc + nt * 16 + ln;
                float bv = bias[col];
                #pragma unroll
                for (int r = 0; r < 4; ++r) {
                    int row = m0 + wr + mt * 16 + qd * 4 + r;
                    float v = acc[mt][nt][r] + bv;
                    if (MODE == 1) ((float*)Cout)[(size_t)row * EMBED + col] = v;
                    else           ((bf16*)Cout)[(size_t)row * EMBED + col] = (bf16)v;
                }
            }
        }
    }
}

__global__ __launch_bounds__(256) void gemm_qk_kernel(
        const bf16* __restrict__ A,
        const bf16* __restrict__ B0, const bf16* __restrict__ B1,
        const float* __restrict__ b0, const float* __restrict__ b1,
        bf16* __restrict__ C0, bf16* __restrict__ C1) {
    if (blockIdx.z == 0) gemm_body<0>(A, B0, b0, (void*)C0);
    else                 gemm_body<0>(A, B1, b1, (void*)C1);
}

__global__ __launch_bounds__(256) void gemm_v_kernel(
        const bf16* __restrict__ A, const bf16* __restrict__ Bm,
        const float* __restrict__ bias, bf16* __restrict__ Vt) {
    gemm_body<2>(A, Bm, bias, (void*)Vt);
}

__global__ __launch_bounds__(256) void gemm_o_kernel(
        const bf16* __restrict__ A, const bf16* __restrict__ Bm,
        const float* __restrict__ bias, float* __restrict__ C) {
    gemm_body<1>(A, Bm, bias, (void*)C);
}

// ---------------- row sum of exp (S^T orientation) ----------------
// grid (16 qb, 16 kb, 32 bh), block 256. Per block: 128 qrows x 128 kcols.
// A = K rows (m=kcol), B = Q rows (n=qrow). atomicAdd partial row sums into l.
__global__ __launch_bounds__(256) void sumexp_kernel(const bf16* __restrict__ Q,
                                                     const bf16* __restrict__ K,
                                                     float* __restrict__ l) {
    const int qb = blockIdx.x, kb = blockIdx.y, bh = blockIdx.z;
    const int b = bh >> 4, h = bh & 15;
    const size_t rowbase = (size_t)b * SEQ;
    const int colbase = h * DH;
    __shared__ bf16 Ks[128 * 72];                 // padded +8: 2-way-free reads
    const int tid = threadIdx.x, wave = tid >> 6, lane = tid & 63;
    const int qd = lane >> 4, ln = lane & 15;
    {
        int row = tid >> 1, c0 = (tid & 1) * 32;
        const bf16* kp = K + (rowbase + kb * 128 + row) * EMBED + colbase + c0;
        #pragma unroll
        for (int j = 0; j < 4; ++j)
            *(bf16x8*)(Ks + row * 72 + c0 + j * 8) = *(const bf16x8*)(kp + j * 8);
    }
    __syncthreads();
    bf16x8 qf[2][2];                              // [ni][kk] loop-invariant Q frags
    #pragma unroll
    for (int ni = 0; ni < 2; ++ni)
        #pragma unroll
        for (int kkid = 0; kkid < 2; ++kkid)
            qf[ni][kkid] = *(const bf16x8*)(
                Q + (rowbase + qb * 128 + wave * 32 + ni * 16 + ln) * EMBED +
                colbase + kkid * 32 + qd * 8);
    float ssum[2] = {0.f, 0.f};
    #pragma unroll
    for (int mi = 0; mi < 8; ++mi) {
        bf16x8 kf[2];
        #pragma unroll
        for (int kkid = 0; kkid < 2; ++kkid)
            kf[kkid] = *(const bf16x8*)(Ks + (mi * 16 + ln) * 72 + kkid * 32 + qd * 8);
        #pragma unroll
        for (int ni = 0; ni < 2; ++ni) {
            f32x4 acc = {};
            acc = __builtin_amdgcn_mfma_f32_16x16x32_bf16(kf[0], qf[ni][0], acc, 0, 0, 0);
            acc = __builtin_amdgcn_mfma_f32_16x16x32_bf16(kf[1], qf[ni][1], acc, 0, 0, 0);
            #pragma unroll
            for (int r = 0; r < 4; ++r) ssum[ni] += __expf(acc[r] * 0.125f);
        }
    }
    #pragma unroll
    for (int ni = 0; ni < 2; ++ni) {
        float s = ssum[ni];
        s += __shfl_xor(s, 16);
        s += __shfl_xor(s, 32);
        if (lane < 16)
            atomicAdd(l + (size_t)bh * SEQ + qb * 128 + wave * 32 + ni * 16 + ln, s);
    }
}

// ---------------- single-pass PV + weights write ----------------
// grid (32 qb, 32 bh), block 256 (4 waves). 64 qrows per block, 64 kcols per iter.
// S^T via MFMA(A=K, B=Q-regs): lane holds 4 consecutive kcols of one qrow ->
// dwordx4 weights store + b64 Pt write. PV: A=Pt rows, B=Vts rows.
__global__ __launch_bounds__(256) void attn_pv_kernel(
        const bf16* __restrict__ Q, const bf16* __restrict__ K,
        const bf16* __restrict__ Vt, const float* __restrict__ l,
        float* __restrict__ Wout, bf16* __restrict__ O) {
    const int qb = blockIdx.x, bh = blockIdx.y;
    const int b = bh >> 4, h = bh & 15;
    const size_t rowbase = (size_t)b * SEQ;
    const int colbase = h * DH;
    __shared__ bf16 Ks[64 * 72];
    __shared__ bf16 Vts[64 * 72];
    __shared__ bf16 Pt[64 * 72];
    const int tid = threadIdx.x, wave = tid >> 6, lane = tid & 63;
    const int qd = lane >> 4, ln = lane & 15;
    const int qrow = qb * 64 + wave * 16 + ln;    // this lane's qrow (for S^T / W)

    bf16x8 qf[2];
    qf[0] = *(const bf16x8*)(Q + (rowbase + qrow) * EMBED + colbase + qd * 8);
    qf[1] = *(const bf16x8*)(Q + (rowbase + qrow) * EMBED + colbase + 32 + qd * 8);
    const float rl = 1.0f / l[(size_t)bh * SEQ + qrow];

    f32x4 oacc[4] = {};
    const int srow = tid >> 2, sc = (tid & 3) * 16;
    const bf16* kp = K + (rowbase + srow) * EMBED + colbase + sc;
    const bf16* vp = Vt + ((size_t)bh * DH + srow) * SEQ + sc;
    float* wrow = Wout + ((size_t)bh * SEQ + qrow) * SEQ;

    for (int kb = 0; kb < 32; ++kb) {
        bf16x8 k0 = *(const bf16x8*)(kp + (size_t)kb * 64 * EMBED);
        bf16x8 k1 = *(const bf16x8*)(kp + (size_t)kb * 64 * EMBED + 8);
        bf16x8 v0 = *(const bf16x8*)(vp + kb * 64);
        bf16x8 v1 = *(const bf16x8*)(vp + kb * 64 + 8);
        *(bf16x8*)(Ks + srow * 72 + sc) = k0;
        *(bf16x8*)(Ks + srow * 72 + sc + 8) = k1;
        *(bf16x8*)(Vts + srow * 72 + sc) = v0;
        *(bf16x8*)(Vts + srow * 72 + sc + 8) = v1;
        __syncthreads();
        // scores (S^T): 4 m-tiles of 16 kcols
        #pragma unroll
        for (int mi = 0; mi < 4; ++mi) {
            f32x4 acc = {};
            #pragma unroll
            for (int kkid = 0; kkid < 2; ++kkid) {
                bf16x8 kf = *(const bf16x8*)(Ks + (mi * 16 + ln) * 72 + kkid * 32 + qd * 8);
                acc = __builtin_amdgcn_mfma_f32_16x16x32_bf16(kf, qf[kkid], acc, 0, 0, 0);
            }
            float4 pw; bf16x4 pb;
            #pragma unroll
            for (int r = 0; r < 4; ++r) {
                float p = __expf(acc[r] * 0.125f) * rl;
                ((float*)&pw)[r] = p;
                pb[r] = (bf16)p;
            }
            *(float4*)(wrow + kb * 64 + mi * 16 + qd * 4) = pw;
            *(bf16x4*)(Pt + (wave * 16 + ln) * 72 + mi * 16 + qd * 4) = pb;
        }
        // PV: own-wave Pt rows (within-wave lgkmcnt ordering suffices)
        #pragma unroll
        for (int kkid = 0; kkid < 2; ++kkid) {
            bf16x8 pf = *(const bf16x8*)(Pt + (wave * 16 + ln) * 72 + kkid * 32 + qd * 8);
            #pragma unroll
            for (int ni = 0; ni < 4; ++ni) {
                bf16x8 vf = *(const bf16x8*)(Vts + (ni * 16 + ln) * 72 + kkid * 32 + qd * 8);
                oacc[ni] = __builtin_amdgcn_mfma_f32_16x16x32_bf16(pf, vf, oacc[ni], 0, 0, 0);
            }
        }
        __syncthreads();
    }
    // O tile: lane holds rows wave*16+qd*4+r, col d=ni*16+ln
    #pragma unroll
    for (int ni = 0; ni < 4; ++ni)
        #pragma unroll
        for (int r = 0; r < 4; ++r)
            O[(rowbase + qb * 64 + wave * 16 + qd * 4 + r) * EMBED + colbase + ni * 16 + ln] =
                (bf16)oacc[ni][r];
}

// ---------------- launch ----------------
extern "C" void kernel_launch(void* const* d_in, const int* in_sizes, int n_in,
                              void* d_out, int out_size, void* d_ws, size_t ws_size,
                              hipStream_t stream) {
    const float* x  = (const float*)d_in[0];
    const float* Wq = (const float*)d_in[1];
    const float* bq = (const float*)d_in[2];
    const float* Wk = (const float*)d_in[3];
    const float* bk = (const float*)d_in[4];
    const float* Wv = (const float*)d_in[5];
    const float* bv = (const float*)d_in[6];
    const float* Wo = (const float*)d_in[7];
    const float* bo = (const float*)d_in[8];

    float* out0 = (float*)d_out;                         // [2,2048,1024]
    float* Wout = (float*)d_out + (size_t)MROWS * EMBED; // weights [2,16,2048,2048]

    const size_t MB = 1u << 20;
    char* ws = (char*)d_ws;
    bf16*  Xb  = (bf16*)(ws + 0 * MB);   // 8 MB (dead after QKV gemms)
    float* lb  = (float*)(ws + 0 * MB);  // 256 KB, reuses Xb region
    bf16*  Wqb = (bf16*)(ws + 8 * MB);
    bf16*  Wkb = (bf16*)(ws + 10 * MB);
    bf16*  Wvb = (bf16*)(ws + 12 * MB);
    bf16*  Wob = (bf16*)(ws + 14 * MB);
    bf16*  Qb  = (bf16*)(ws + 16 * MB);  // 8 MB
    bf16*  Kb  = (bf16*)(ws + 24 * MB);
    bf16*  Vt  = (bf16*)(ws + 32 * MB);  // 8 MB, [32 bh][64 d][2048 s]
    bf16*  Ob  = (bf16*)(ws + 40 * MB);  // 8 MB -> total 48 MB

    cvt_x_kernel<<<4096, 256, 0, stream>>>(x, Xb);
    cvt_wt_kernel<<<dim3(32, 32, 4), 256, 0, stream>>>(Wq, Wk, Wv, Wo, Wqb, Wkb, Wvb, Wob);
    gemm_qk_kernel<<<dim3(8, 32, 2), 256, 0, stream>>>(Xb, Wqb, Wkb, bq, bk, Qb, Kb);
    gemm_v_kernel<<<dim3(8, 32), 256, 0, stream>>>(Xb, Wvb, bv, Vt);
    zero_l_kernel<<<64, 256, 0, stream>>>(lb);
    sumexp_kernel<<<dim3(16, 16, 32), 256, 0, stream>>>(Qb, Kb, lb);
    attn_pv_kernel<<<dim3(32, 32), 256, 0, stream>>>(Qb, Kb, Vt, lb, Wout, Ob);
    gemm_o_kernel<<<dim3(8, 32), 256, 0, stream>>>(Ob, Wob, bo, out0);
}